// Round 1
// baseline (304.017 us; speedup 1.0000x reference)
//
#include <hip/hip_runtime.h>
#include <stdint.h>

// SMHA: sigmoid multi-head attention, L=2048 B=2 E=1024 H=16 hd=64.
// Pipeline: convert(f32->bf16) -> inproj GEMM -> fused sigmoid attention
//           -> avg_weights (head-summed sigmoid scores) -> outproj GEMM.

#define L_SEQ 2048
#define NBATCH 2
#define EMB 1024
#define NHEAD 16
#define HD 64
#define MROWS 4096  // B*L

typedef __bf16 bf16x8 __attribute__((ext_vector_type(8)));
typedef float f32x4 __attribute__((ext_vector_type(4)));

__device__ __forceinline__ unsigned short f2bf(float f) {
  union { float f; uint32_t u; } v; v.f = f;
  uint32_t u = v.u;
  u += 0x7fffu + ((u >> 16) & 1u);  // RNE
  return (unsigned short)(u >> 16);
}

// global -> LDS direct DMA, 16B per lane. LDS base must be wave-uniform;
// lane i lands at base + i*16. Global ptr is per-lane (we exploit this for
// the XOR chunk swizzle).
__device__ __forceinline__ void gl_lds16(const void* gptr, void* ldsptr) {
  const uint32_t* g = reinterpret_cast<const uint32_t*>(gptr);
  auto* l = reinterpret_cast<__attribute__((address_space(3))) uint32_t*>(
      reinterpret_cast<uintptr_t>(ldsptr));
  __builtin_amdgcn_global_load_lds(g, l, 16, 0, 0);
}

__device__ __forceinline__ f32x4 mfma16(bf16x8 a, bf16x8 b, f32x4 c) {
  return __builtin_amdgcn_mfma_f32_16x16x32_bf16(a, b, c, 0, 0, 0);
}

__device__ __forceinline__ float fast_sigmoid(float x) {
  float e = __expf(-x);
  return __builtin_amdgcn_rcpf(1.0f + e);
}

// ---------------------------------------------------------------- K0: convert
// Rows 0..12287: query/key/value (L,B,E) f32 -> X* bf16 with row m = b*L + l.
// Rows 12288..15359: in_proj_weight. Rows 15360..16383: out_w.
__global__ __launch_bounds__(256) void k_convert(
    const float* __restrict__ qin, const float* __restrict__ kin,
    const float* __restrict__ vin, const float* __restrict__ win,
    const float* __restrict__ wo,
    unsigned short* __restrict__ Xq, unsigned short* __restrict__ Xk,
    unsigned short* __restrict__ Xv, unsigned short* __restrict__ Wb,
    unsigned short* __restrict__ Wob) {
  const int row = blockIdx.x;
  const int t = threadIdx.x;
  const float* src;
  unsigned short* dst;
  int srow;
  size_t drow;
  if (row < 3 * MROWS) {
    const int which = row >> 12;
    const int m = row & (MROWS - 1);
    const int b = m >> 11, l = m & (L_SEQ - 1);
    srow = l * NBATCH + b;  // input rows are (l, b)
    drow = (size_t)m;
    src = which == 0 ? qin : (which == 1 ? kin : vin);
    dst = which == 0 ? Xq : (which == 1 ? Xk : Xv);
  } else if (row < 3 * MROWS + 3072) {
    srow = row - 3 * MROWS; drow = (size_t)srow; src = win; dst = Wb;
  } else {
    srow = row - (3 * MROWS + 3072); drow = (size_t)srow; src = wo; dst = Wob;
  }
  const float4 vv = *(const float4*)(src + (size_t)srow * EMB + t * 4);
  ushort4 o;
  o.x = f2bf(vv.x); o.y = f2bf(vv.y); o.z = f2bf(vv.z); o.w = f2bf(vv.w);
  *(ushort4*)(dst + drow * EMB + t * 4) = o;
}

// --------------------------------------------------- shared GEMM core (BT)
// C[128x128] tile of A(MxK row-major) * B(NxK row-major)^T, K=1024, BK=32.
// LDS chunk swizzle: row r, 8-elem chunk c stored at slot c ^ ((r>>1)&3).
__device__ __forceinline__ void gemm_core(
    const unsigned short* __restrict__ A, const unsigned short* __restrict__ Bm,
    int m0, int n0, unsigned short* sA, unsigned short* sB, f32x4 acc[4][4]) {
  const int tid = threadIdx.x;
  const int wave = tid >> 6;
  const int lane = tid & 63;
  const int quad = lane >> 4;
  const int l16 = lane & 15;
  const int wm = (wave >> 1) * 64;
  const int wn = (wave & 1) * 64;
  const int srow = lane >> 2;  // 0..15 within a 16-row chunk
  const int scol = lane & 3;   // LDS chunk slot

  for (int mi = 0; mi < 4; ++mi)
    for (int ni = 0; ni < 4; ++ni)
      acc[mi][ni] = (f32x4){0.f, 0.f, 0.f, 0.f};

  for (int k0 = 0; k0 < EMB; k0 += 32) {
    __syncthreads();
    for (int i = 0; i < 2; ++i) {
      const int p = wave * 2 + i;
      const int r = p * 16 + srow;
      const int c = scol ^ ((r >> 1) & 3);
      gl_lds16(A + (size_t)(m0 + r) * EMB + k0 + c * 8, sA + p * 512);
      gl_lds16(Bm + (size_t)(n0 + r) * EMB + k0 + c * 8, sB + p * 512);
    }
    __syncthreads();
    bf16x8 af[4], bfr[4];
    for (int mi = 0; mi < 4; ++mi) {
      const int r = wm + mi * 16 + l16;
      const int cp = quad ^ ((r >> 1) & 3);
      af[mi] = *(const bf16x8*)(sA + r * 32 + cp * 8);
    }
    for (int ni = 0; ni < 4; ++ni) {
      const int r = wn + ni * 16 + l16;
      const int cp = quad ^ ((r >> 1) & 3);
      bfr[ni] = *(const bf16x8*)(sB + r * 32 + cp * 8);
    }
    for (int mi = 0; mi < 4; ++mi)
      for (int ni = 0; ni < 4; ++ni)
        acc[mi][ni] = mfma16(af[mi], bfr[ni], acc[mi][ni]);
  }
}

// ---------------------------------------------------------------- K1: inproj
// z=0: q (scaled 1/8) -> (b,h,l,d); z=1: k -> (b,h,l,d); z=2: v -> (b,h,d,l).
__global__ __launch_bounds__(256) void k_inproj(
    const unsigned short* __restrict__ Xq, const unsigned short* __restrict__ Xk,
    const unsigned short* __restrict__ Xv, const unsigned short* __restrict__ Wb,
    const float* __restrict__ bias,
    unsigned short* __restrict__ qb, unsigned short* __restrict__ kb,
    unsigned short* __restrict__ vb) {
  __shared__ __attribute__((aligned(16))) unsigned short sA[128 * 32];
  __shared__ __attribute__((aligned(16))) unsigned short sB[128 * 32];
  const int z = blockIdx.z;
  const unsigned short* A = z == 0 ? Xq : (z == 1 ? Xk : Xv);
  const int n0 = blockIdx.x * 128, m0 = blockIdx.y * 128;
  f32x4 acc[4][4];
  gemm_core(A, Wb + (size_t)z * EMB * EMB, m0, n0, sA, sB, acc);

  const int tid = threadIdx.x, wave = tid >> 6, lane = tid & 63;
  const int quad = lane >> 4, l16 = lane & 15;
  const int wm = (wave >> 1) * 64, wn = (wave & 1) * 64;
  const float scale = (z == 0) ? 0.125f : 1.0f;
  unsigned short* dst01 = (z == 0) ? qb : kb;
  for (int ni = 0; ni < 4; ++ni) {
    const int n = n0 + wn + ni * 16 + l16;
    const float bv = bias[z * EMB + n];
    const int h = n >> 6, d = n & 63;
    for (int mi = 0; mi < 4; ++mi) {
      for (int r = 0; r < 4; ++r) {
        const int m = m0 + wm + mi * 16 + quad * 4 + r;
        const int b = m >> 11, l = m & (L_SEQ - 1);
        const unsigned short o = f2bf((acc[mi][ni][r] + bv) * scale);
        if (z == 2)
          vb[((size_t)(b * NHEAD + h) * HD + d) * L_SEQ + l] = o;
        else
          dst01[((size_t)(b * NHEAD + h) * L_SEQ + l) * HD + d] = o;
      }
    }
  }
}

// --------------------------------------------------------------- K2: attention
// One block per (b*H+h, l-tile of 128). Single pass over S (sigmoid: no
// online rescale). S^T = K*Q^T so P lands in LDS via contiguous ds_write_b64.
__global__ __launch_bounds__(256) void k_attn(
    const unsigned short* __restrict__ qb, const unsigned short* __restrict__ kb,
    const unsigned short* __restrict__ vb, unsigned short* __restrict__ oh) {
  __shared__ __attribute__((aligned(16))) unsigned short sQ[128 * 64];
  __shared__ __attribute__((aligned(16))) unsigned short sK[64 * 64];
  __shared__ __attribute__((aligned(16))) unsigned short sV[64 * 64];
  __shared__ __attribute__((aligned(16))) unsigned short sP[128 * 72];  // +8 pad
  __shared__ float sDen[128];

  const int bh = blockIdx.x;
  const int b = bh >> 4, h = bh & 15;
  const int l0 = blockIdx.y * 128;
  const unsigned short* qg = qb + ((size_t)bh * L_SEQ + l0) * HD;
  const unsigned short* kg = kb + (size_t)bh * L_SEQ * HD;
  const unsigned short* vg = vb + (size_t)bh * HD * L_SEQ;

  const int tid = threadIdx.x, wave = tid >> 6, lane = tid & 63;
  const int quad = lane >> 4, l16 = lane & 15;
  const int lw = wave * 32;     // wave's l-range [lw, lw+32)
  const int sr8 = lane >> 3;    // row within 8-row staging chunk
  const int sc8 = lane & 7;     // LDS chunk slot

  // stage Q tile (128 x 64) once
  for (int i = 0; i < 4; ++i) {
    const int p = wave * 4 + i;
    const int r = p * 8 + sr8;
    const int c = sc8 ^ (r & 7);
    gl_lds16(qg + (size_t)r * HD + c * 8, sQ + p * 512);
  }

  f32x4 oacc[2][4];
  for (int mi = 0; mi < 2; ++mi)
    for (int ni = 0; ni < 4; ++ni) oacc[mi][ni] = (f32x4){0.f, 0.f, 0.f, 0.f};
  float den[2] = {0.f, 0.f};

  for (int s0 = 0; s0 < L_SEQ; s0 += 64) {
    __syncthreads();  // prev iter's LDS reads done (iter0: Q visible after this)
    for (int i = 0; i < 2; ++i) {
      const int p = wave * 2 + i;
      const int r = p * 8 + sr8;
      const int c = sc8 ^ (r & 7);
      gl_lds16(kg + (size_t)(s0 + r) * HD + c * 8, sK + p * 512);
      gl_lds16(vg + (size_t)r * L_SEQ + s0 + c * 8, sV + p * 512);
    }
    __syncthreads();  // staging visible

    // S^T tile: m = s (64), n = wave's 32 l's
    f32x4 st[4][2];
    for (int smi = 0; smi < 4; ++smi)
      for (int lni = 0; lni < 2; ++lni) st[smi][lni] = (f32x4){0.f, 0.f, 0.f, 0.f};
    for (int kk = 0; kk < HD; kk += 32) {
      bf16x8 a[4], bq[2];
      for (int smi = 0; smi < 4; ++smi) {
        const int r = smi * 16 + l16;
        const int c = ((kk >> 3) + quad) ^ (r & 7);
        a[smi] = *(const bf16x8*)(sK + r * 64 + c * 8);
      }
      for (int lni = 0; lni < 2; ++lni) {
        const int r = lw + lni * 16 + l16;
        const int c = ((kk >> 3) + quad) ^ (r & 7);
        bq[lni] = *(const bf16x8*)(sQ + r * 64 + c * 8);
      }
      for (int smi = 0; smi < 4; ++smi)
        for (int lni = 0; lni < 2; ++lni)
          st[smi][lni] = mfma16(a[smi], bq[lni], st[smi][lni]);
    }

    // sigmoid + denom accumulation + P -> LDS (l,s) layout, stride 72
    for (int lni = 0; lni < 2; ++lni) {
      const int lrow = lw + lni * 16 + l16;
      for (int smi = 0; smi < 4; ++smi) {
        const float p0 = fast_sigmoid(st[smi][lni][0]);
        const float p1 = fast_sigmoid(st[smi][lni][1]);
        const float p2 = fast_sigmoid(st[smi][lni][2]);
        const float p3 = fast_sigmoid(st[smi][lni][3]);
        den[lni] += (p0 + p1) + (p2 + p3);
        ushort4 pk;
        pk.x = f2bf(p0); pk.y = f2bf(p1); pk.z = f2bf(p2); pk.w = f2bf(p3);
        *(ushort4*)(sP + (size_t)lrow * 72 + smi * 16 + quad * 4) = pk;
      }
    }
    __syncthreads();  // P visible

    // out += P * V  (A = P from sP, B = V from sV (d,s) layout)
    for (int kk = 0; kk < 64; kk += 32) {
      bf16x8 ap[2], bv4[4];
      for (int mi = 0; mi < 2; ++mi) {
        const int r = lw + mi * 16 + l16;
        ap[mi] = *(const bf16x8*)(sP + r * 72 + kk + quad * 8);
      }
      for (int ni = 0; ni < 4; ++ni) {
        const int rd = ni * 16 + l16;
        const int c = ((kk >> 3) + quad) ^ (rd & 7);
        bv4[ni] = *(const bf16x8*)(sV + rd * 64 + c * 8);
      }
      for (int mi = 0; mi < 2; ++mi)
        for (int ni = 0; ni < 4; ++ni)
          oacc[mi][ni] = mfma16(ap[mi], bv4[ni], oacc[mi][ni]);
    }
  }

  // reduce denom across quads, store reciprocal
  for (int lni = 0; lni < 2; ++lni) {
    float d2 = den[lni];
    d2 += __shfl_xor(d2, 16, 64);
    d2 += __shfl_xor(d2, 32, 64);
    if (quad == 0) sDen[lw + lni * 16 + l16] = __builtin_amdgcn_rcpf(d2 + 1e-4f);
  }
  __syncthreads();

  // normalize + write out_head bf16 at (b, l, e=h*64+d)
  for (int mi = 0; mi < 2; ++mi) {
    for (int r = 0; r < 4; ++r) {
      const int lrow = lw + mi * 16 + quad * 4 + r;
      const float rden = sDen[lrow];
      unsigned short* dst =
          oh + ((size_t)(b * L_SEQ + l0 + lrow)) * EMB + h * HD;
      for (int ni = 0; ni < 4; ++ni)
        dst[ni * 16 + l16] = f2bf(oacc[mi][ni][r] * rden);
    }
  }
}

// ---------------------------------------------------------------- K3: avg
// One block per (s-tile 128, l-tile 128, b): avg = (1/16) sum_h sigmoid(QK^T).
__global__ __launch_bounds__(256) void k_avg(
    const unsigned short* __restrict__ qb, const unsigned short* __restrict__ kb,
    float* __restrict__ avg) {
  __shared__ __attribute__((aligned(16))) unsigned short sQ[128 * 64];
  __shared__ __attribute__((aligned(16))) unsigned short sK[128 * 64];
  const int ss0 = blockIdx.x * 128, l0 = blockIdx.y * 128, b = blockIdx.z;
  const int tid = threadIdx.x, wave = tid >> 6, lane = tid & 63;
  const int quad = lane >> 4, l16 = lane & 15;
  const int wm = (wave >> 1) * 64, wn = (wave & 1) * 64;
  const int sr8 = lane >> 3, sc8 = lane & 7;

  f32x4 av[4][4];
  for (int mi = 0; mi < 4; ++mi)
    for (int ni = 0; ni < 4; ++ni) av[mi][ni] = (f32x4){0.f, 0.f, 0.f, 0.f};

  for (int h = 0; h < NHEAD; ++h) {
    const unsigned short* qg = qb + ((size_t)(b * NHEAD + h) * L_SEQ + l0) * HD;
    const unsigned short* kg = kb + ((size_t)(b * NHEAD + h) * L_SEQ + ss0) * HD;
    __syncthreads();
    for (int i = 0; i < 4; ++i) {
      const int p = wave * 4 + i;
      const int r = p * 8 + sr8;
      const int c = sc8 ^ (r & 7);
      gl_lds16(qg + (size_t)r * HD + c * 8, sQ + p * 512);
      gl_lds16(kg + (size_t)r * HD + c * 8, sK + p * 512);
    }
    __syncthreads();
    f32x4 scr[4][4];
    for (int mi = 0; mi < 4; ++mi)
      for (int ni = 0; ni < 4; ++ni) scr[mi][ni] = (f32x4){0.f, 0.f, 0.f, 0.f};
    for (int kk = 0; kk < HD; kk += 32) {
      bf16x8 a[4], bb[4];
      for (int mi = 0; mi < 4; ++mi) {
        const int r = wm + mi * 16 + l16;
        const int c = ((kk >> 3) + quad) ^ (r & 7);
        a[mi] = *(const bf16x8*)(sQ + r * 64 + c * 8);
      }
      for (int ni = 0; ni < 4; ++ni) {
        const int r = wn + ni * 16 + l16;
        const int c = ((kk >> 3) + quad) ^ (r & 7);
        bb[ni] = *(const bf16x8*)(sK + r * 64 + c * 8);
      }
      for (int mi = 0; mi < 4; ++mi)
        for (int ni = 0; ni < 4; ++ni)
          scr[mi][ni] = mfma16(a[mi], bb[ni], scr[mi][ni]);
    }
    for (int mi = 0; mi < 4; ++mi)
      for (int ni = 0; ni < 4; ++ni)
        for (int r = 0; r < 4; ++r)
          av[mi][ni][r] += fast_sigmoid(scr[mi][ni][r]);
  }

  for (int mi = 0; mi < 4; ++mi) {
    for (int r = 0; r < 4; ++r) {
      const int l = l0 + wm + mi * 16 + quad * 4 + r;
      float* dst = avg + ((size_t)b * L_SEQ + l) * L_SEQ + ss0 + wn;
      for (int ni = 0; ni < 4; ++ni)
        dst[ni * 16 + l16] = av[mi][ni][r] * 0.0625f;
    }
  }
}

// ---------------------------------------------------------------- K4: outproj
__global__ __launch_bounds__(256) void k_outproj(
    const unsigned short* __restrict__ OH, const unsigned short* __restrict__ Wob,
    const float* __restrict__ ob, float* __restrict__ out) {
  __shared__ __attribute__((aligned(16))) unsigned short sA[128 * 32];
  __shared__ __attribute__((aligned(16))) unsigned short sB[128 * 32];
  const int n0 = blockIdx.x * 128, m0 = blockIdx.y * 128;
  f32x4 acc[4][4];
  gemm_core(OH, Wob, m0, n0, sA, sB, acc);

  const int tid = threadIdx.x, wave = tid >> 6, lane = tid & 63;
  const int quad = lane >> 4, l16 = lane & 15;
  const int wm = (wave >> 1) * 64, wn = (wave & 1) * 64;
  for (int ni = 0; ni < 4; ++ni) {
    const int n = n0 + wn + ni * 16 + l16;
    const float bv = ob[n];
    for (int mi = 0; mi < 4; ++mi) {
      for (int r = 0; r < 4; ++r) {
        const int m = m0 + wm + mi * 16 + quad * 4 + r;
        const int b = m >> 11, l = m & (L_SEQ - 1);
        out[((size_t)l * NBATCH + b) * EMB + n] = acc[mi][ni][r] + bv;
      }
    }
  }
}

extern "C" void kernel_launch(void* const* d_in, const int* in_sizes, int n_in,
                              void* d_out, int out_size, void* d_ws, size_t ws_size,
                              hipStream_t stream) {
  (void)in_sizes; (void)n_in; (void)out_size;
  const float* qin = (const float*)d_in[0];
  const float* kin = (const float*)d_in[1];
  const float* vin = (const float*)d_in[2];
  const float* w   = (const float*)d_in[3];
  const float* bias = (const float*)d_in[4];
  const float* wo  = (const float*)d_in[5];
  const float* ob  = (const float*)d_in[6];
  float* out = (float*)d_out;

  // workspace layout (bf16 elements)
  unsigned short* Xq  = (unsigned short*)d_ws;
  unsigned short* Xk  = Xq + (size_t)MROWS * EMB;       // 4M
  unsigned short* Xv  = Xk + (size_t)MROWS * EMB;       // 4M
  unsigned short* Wb  = Xv + (size_t)MROWS * EMB;       // 3M
  unsigned short* Wob = Wb + (size_t)3 * EMB * EMB;     // 1M
  unsigned short* qbuf = Wob + (size_t)EMB * EMB;       // 4M
  unsigned short* kbuf = qbuf + (size_t)MROWS * EMB;    // 4M
  unsigned short* vbuf = kbuf + (size_t)MROWS * EMB;    // 4M
  unsigned short* ohb  = vbuf + (size_t)MROWS * EMB;    // 4M
  const size_t need = ((size_t)MROWS * EMB * 7 + (size_t)4 * EMB * EMB) * 2;
  if (ws_size < need) return;  // workspace too small: fail loudly (wrong output)

  k_convert<<<16384, 256, 0, stream>>>(qin, kin, vin, w, wo, Xq, Xk, Xv, Wb, Wob);
  k_inproj<<<dim3(8, 32, 3), 256, 0, stream>>>(Xq, Xk, Xv, Wb, bias, qbuf, kbuf, vbuf);
  k_attn<<<dim3(32, 16), 256, 0, stream>>>(qbuf, kbuf, vbuf, ohb);
  k_avg<<<dim3(16, 16, 2), 256, 0, stream>>>(qbuf, kbuf, out + (size_t)MROWS * EMB);
  k_outproj<<<dim3(8, 32), 256, 0, stream>>>(ohb, Wob, ob, out);
}

// Round 2
// 275.667 us; speedup vs baseline: 1.1028x; 1.1028x over previous
//
#include <hip/hip_runtime.h>
#include <stdint.h>

// SMHA: sigmoid multi-head attention, L=2048 B=2 E=1024 H=16 hd=64.
// Pipeline: convert(f32->bf16) -> inproj GEMM -> fused sigmoid attention
//           -> avg_weights (head-summed sigmoid scores) -> outproj GEMM.

#define L_SEQ 2048
#define NBATCH 2
#define EMB 1024
#define NHEAD 16
#define HD 64
#define MROWS 4096  // B*L

typedef __bf16 bf16x8 __attribute__((ext_vector_type(8)));
typedef float f32x4 __attribute__((ext_vector_type(4)));

__device__ __forceinline__ unsigned short f2bf(float f) {
  union { float f; uint32_t u; } v; v.f = f;
  uint32_t u = v.u;
  u += 0x7fffu + ((u >> 16) & 1u);  // RNE
  return (unsigned short)(u >> 16);
}

// cheap bf16 (round-half-up): fine for values far from NaN/inf
__device__ __forceinline__ unsigned short f2bf_fast(float f) {
  union { float f; uint32_t u; } v; v.f = f;
  return (unsigned short)((v.u + 0x8000u) >> 16);
}

__device__ __forceinline__ void gl_lds16(const void* gptr, void* ldsptr) {
  const uint32_t* g = reinterpret_cast<const uint32_t*>(gptr);
  auto* l = reinterpret_cast<__attribute__((address_space(3))) uint32_t*>(
      reinterpret_cast<uintptr_t>(ldsptr));
  __builtin_amdgcn_global_load_lds(g, l, 16, 0, 0);
}

__device__ __forceinline__ f32x4 mfma16(bf16x8 a, bf16x8 b, f32x4 c) {
  return __builtin_amdgcn_mfma_f32_16x16x32_bf16(a, b, c, 0, 0, 0);
}

__device__ __forceinline__ float fast_sigmoid(float x) {
  float e = __expf(-x);
  return __builtin_amdgcn_rcpf(1.0f + e);
}

// ---------------------------------------------------------------- K0: convert
__global__ __launch_bounds__(256) void k_convert(
    const float* __restrict__ qin, const float* __restrict__ kin,
    const float* __restrict__ vin, const float* __restrict__ win,
    const float* __restrict__ wo,
    unsigned short* __restrict__ Xq, unsigned short* __restrict__ Xk,
    unsigned short* __restrict__ Xv, unsigned short* __restrict__ Wb,
    unsigned short* __restrict__ Wob) {
  const int row = blockIdx.x;
  const int t = threadIdx.x;
  const float* src;
  unsigned short* dst;
  int srow;
  size_t drow;
  if (row < 3 * MROWS) {
    const int which = row >> 12;
    const int m = row & (MROWS - 1);
    const int b = m >> 11, l = m & (L_SEQ - 1);
    srow = l * NBATCH + b;  // input rows are (l, b)
    drow = (size_t)m;
    src = which == 0 ? qin : (which == 1 ? kin : vin);
    dst = which == 0 ? Xq : (which == 1 ? Xk : Xv);
  } else if (row < 3 * MROWS + 3072) {
    srow = row - 3 * MROWS; drow = (size_t)srow; src = win; dst = Wb;
  } else {
    srow = row - (3 * MROWS + 3072); drow = (size_t)srow; src = wo; dst = Wob;
  }
  const float4 vv = *(const float4*)(src + (size_t)srow * EMB + t * 4);
  ushort4 o;
  o.x = f2bf(vv.x); o.y = f2bf(vv.y); o.z = f2bf(vv.z); o.w = f2bf(vv.w);
  *(ushort4*)(dst + drow * EMB + t * 4) = o;
}

// --------------------------------------------------- shared GEMM core (BT)
__device__ __forceinline__ void gemm_core(
    const unsigned short* __restrict__ A, const unsigned short* __restrict__ Bm,
    int m0, int n0, unsigned short* sA, unsigned short* sB, f32x4 acc[4][4]) {
  const int tid = threadIdx.x;
  const int wave = tid >> 6;
  const int lane = tid & 63;
  const int quad = lane >> 4;
  const int l16 = lane & 15;
  const int wm = (wave >> 1) * 64;
  const int wn = (wave & 1) * 64;
  const int srow = lane >> 2;
  const int scol = lane & 3;

  for (int mi = 0; mi < 4; ++mi)
    for (int ni = 0; ni < 4; ++ni)
      acc[mi][ni] = (f32x4){0.f, 0.f, 0.f, 0.f};

  for (int k0 = 0; k0 < EMB; k0 += 32) {
    __syncthreads();
    for (int i = 0; i < 2; ++i) {
      const int p = wave * 2 + i;
      const int r = p * 16 + srow;
      const int c = scol ^ ((r >> 1) & 3);
      gl_lds16(A + (size_t)(m0 + r) * EMB + k0 + c * 8, sA + p * 512);
      gl_lds16(Bm + (size_t)(n0 + r) * EMB + k0 + c * 8, sB + p * 512);
    }
    __syncthreads();
    bf16x8 af[4], bfr[4];
    for (int mi = 0; mi < 4; ++mi) {
      const int r = wm + mi * 16 + l16;
      const int cp = quad ^ ((r >> 1) & 3);
      af[mi] = *(const bf16x8*)(sA + r * 32 + cp * 8);
    }
    for (int ni = 0; ni < 4; ++ni) {
      const int r = wn + ni * 16 + l16;
      const int cp = quad ^ ((r >> 1) & 3);
      bfr[ni] = *(const bf16x8*)(sB + r * 32 + cp * 8);
    }
    for (int mi = 0; mi < 4; ++mi)
      for (int ni = 0; ni < 4; ++ni)
        acc[mi][ni] = mfma16(af[mi], bfr[ni], acc[mi][ni]);
  }
}

// ---------------------------------------------------------------- K1: inproj
__global__ __launch_bounds__(256) void k_inproj(
    const unsigned short* __restrict__ Xq, const unsigned short* __restrict__ Xk,
    const unsigned short* __restrict__ Xv, const unsigned short* __restrict__ Wb,
    const float* __restrict__ bias,
    unsigned short* __restrict__ qb, unsigned short* __restrict__ kb,
    unsigned short* __restrict__ vb) {
  __shared__ __attribute__((aligned(16))) unsigned short sA[128 * 32];
  __shared__ __attribute__((aligned(16))) unsigned short sB[128 * 32];
  const int z = blockIdx.z;
  const unsigned short* A = z == 0 ? Xq : (z == 1 ? Xk : Xv);
  const int n0 = blockIdx.x * 128, m0 = blockIdx.y * 128;
  f32x4 acc[4][4];
  gemm_core(A, Wb + (size_t)z * EMB * EMB, m0, n0, sA, sB, acc);

  const int tid = threadIdx.x, wave = tid >> 6, lane = tid & 63;
  const int quad = lane >> 4, l16 = lane & 15;
  const int wm = (wave >> 1) * 64, wn = (wave & 1) * 64;
  const float scale = (z == 0) ? 0.125f : 1.0f;
  unsigned short* dst01 = (z == 0) ? qb : kb;
  for (int ni = 0; ni < 4; ++ni) {
    const int n = n0 + wn + ni * 16 + l16;
    const float bv = bias[z * EMB + n];
    const int h = n >> 6, d = n & 63;
    for (int mi = 0; mi < 4; ++mi) {
      for (int r = 0; r < 4; ++r) {
        const int m = m0 + wm + mi * 16 + quad * 4 + r;
        const int b = m >> 11, l = m & (L_SEQ - 1);
        const unsigned short o = f2bf((acc[mi][ni][r] + bv) * scale);
        if (z == 2)
          vb[((size_t)(b * NHEAD + h) * HD + d) * L_SEQ + l] = o;
        else
          dst01[((size_t)(b * NHEAD + h) * L_SEQ + l) * HD + d] = o;
      }
    }
  }
}

// --------------------------------------------------------------- K2: attention
// 512 threads / 8 waves. Block = (b*H+h, l-tile 128). s-step 64.
// QK^T computed as S^T = K*Q^T (wave = 32s x 32l); P packed to LDS via
// v_perm; PV with den accumulated by an extra MFMA against a ones fragment
// (den lands in the same C-layout rows as oacc -> no shuffle/LDS reduce).
__global__ __launch_bounds__(512) void k_attn(
    const unsigned short* __restrict__ qb, const unsigned short* __restrict__ kb,
    const unsigned short* __restrict__ vb, unsigned short* __restrict__ oh) {
  __shared__ __attribute__((aligned(16))) unsigned short sQ[128 * 64];
  __shared__ __attribute__((aligned(16))) unsigned short sK[64 * 64];
  __shared__ __attribute__((aligned(16))) unsigned short sV[64 * 64];
  __shared__ __attribute__((aligned(16))) unsigned short sP[128 * 72];

  const int bh = blockIdx.x;
  const int b = bh >> 4, h = bh & 15;
  const int l0 = blockIdx.y * 128;
  const unsigned short* qg = qb + ((size_t)bh * L_SEQ + l0) * HD;
  const unsigned short* kg = kb + (size_t)bh * L_SEQ * HD;
  const unsigned short* vg = vb + (size_t)bh * HD * L_SEQ;

  const int tid = threadIdx.x, wave = tid >> 6, lane = tid & 63;
  const int quad = lane >> 4, l16 = lane & 15;
  const int sr8 = lane >> 3, sc8 = lane & 7;
  const int sh = (wave >> 2) * 32;  // QK: s-half
  const int lq = (wave & 3) * 32;   // QK: l-quarter

  // stage Q (128x64): 16 chunks of 8 rows, 2 per wave
  for (int i = 0; i < 2; ++i) {
    const int p = wave * 2 + i;
    const int r = p * 8 + sr8;
    const int c = sc8 ^ (r & 7);
    gl_lds16(qg + (size_t)r * HD + c * 8, sQ + p * 512);
  }

  f32x4 oacc[4];
  for (int ni = 0; ni < 4; ++ni) oacc[ni] = (f32x4){0.f, 0.f, 0.f, 0.f};
  f32x4 dacc = (f32x4){0.f, 0.f, 0.f, 0.f};

  bf16x8 ones;
  for (int j = 0; j < 8; ++j) ones[j] = (__bf16)1.0f;

  for (int s0 = 0; s0 < L_SEQ; s0 += 64) {
    __syncthreads();  // prev PV reads done (iter0: Q staging ordered too)
    if (wave < 4) {   // waves 0-3 stage K (64x64), 4-7 stage V (64x64, (d,s))
      for (int i = 0; i < 2; ++i) {
        const int p = wave * 2 + i;
        const int r = p * 8 + sr8;
        const int c = sc8 ^ (r & 7);
        gl_lds16(kg + (size_t)(s0 + r) * HD + c * 8, sK + p * 512);
      }
    } else {
      for (int i = 0; i < 2; ++i) {
        const int p = (wave - 4) * 2 + i;
        const int r = p * 8 + sr8;
        const int c = sc8 ^ (r & 7);
        gl_lds16(vg + (size_t)r * L_SEQ + s0 + c * 8, sV + p * 512);
      }
    }
    __syncthreads();  // staging visible

    // S^T tile: wave covers s in [sh,sh+32), l in [lq,lq+32)
    f32x4 st[2][2];
    for (int smi = 0; smi < 2; ++smi)
      for (int lni = 0; lni < 2; ++lni) st[smi][lni] = (f32x4){0.f, 0.f, 0.f, 0.f};
    for (int kk = 0; kk < HD; kk += 32) {
      bf16x8 a[2], bq[2];
      for (int smi = 0; smi < 2; ++smi) {
        const int r = sh + smi * 16 + l16;
        const int c = ((kk >> 3) + quad) ^ (r & 7);
        a[smi] = *(const bf16x8*)(sK + r * 64 + c * 8);
      }
      for (int lni = 0; lni < 2; ++lni) {
        const int r = lq + lni * 16 + l16;
        const int c = ((kk >> 3) + quad) ^ (r & 7);
        bq[lni] = *(const bf16x8*)(sQ + r * 64 + c * 8);
      }
      for (int smi = 0; smi < 2; ++smi)
        for (int lni = 0; lni < 2; ++lni)
          st[smi][lni] = mfma16(a[smi], bq[lni], st[smi][lni]);
    }

    // sigmoid + perm-pack -> sP[l][s_local], stride 72
    for (int lni = 0; lni < 2; ++lni) {
      const int lrow = lq + lni * 16 + l16;
      for (int smi = 0; smi < 2; ++smi) {
        uint32_t u[4];
        for (int r = 0; r < 4; ++r) {
          union { float f; uint32_t i; } cv;
          cv.f = fast_sigmoid(st[smi][lni][r]);
          u[r] = cv.i + 0x8000u;  // round-half-up bf16
        }
        uint2 pk;
        pk.x = __builtin_amdgcn_perm(u[1], u[0], 0x07060302u);
        pk.y = __builtin_amdgcn_perm(u[3], u[2], 0x07060302u);
        *(uint2*)(sP + (size_t)lrow * 72 + sh + smi * 16 + quad * 4) = pk;
      }
    }
    __syncthreads();  // P visible

    // out += P*V ; den += P*1  (wave owns l rows [wave*16, wave*16+16))
    const int lr = wave * 16 + l16;
    for (int kk = 0; kk < 64; kk += 32) {
      bf16x8 ap = *(const bf16x8*)(sP + (size_t)lr * 72 + kk + quad * 8);
      for (int ni = 0; ni < 4; ++ni) {
        const int rd = ni * 16 + l16;
        const int c = ((kk >> 3) + quad) ^ (rd & 7);
        bf16x8 bv4 = *(const bf16x8*)(sV + rd * 64 + c * 8);
        oacc[ni] = mfma16(ap, bv4, oacc[ni]);
      }
      dacc = mfma16(ap, ones, dacc);
    }
  }

  // normalize + write (den rows == oacc rows in C-layout)
  for (int r = 0; r < 4; ++r) {
    const int lrow = l0 + wave * 16 + quad * 4 + r;
    const float rden = __builtin_amdgcn_rcpf(dacc[r] + 1e-4f);
    unsigned short* dst = oh + ((size_t)(b * L_SEQ + lrow)) * EMB + h * HD;
    for (int ni = 0; ni < 4; ++ni)
      dst[ni * 16 + l16] = f2bf_fast(oacc[ni][r] * rden);
  }
}

// ---------------------------------------------------------------- K3: avg
// 512 threads / 8 waves. Block = (s-tile 128, l-tile 128, b).
__global__ __launch_bounds__(512) void k_avg(
    const unsigned short* __restrict__ qb, const unsigned short* __restrict__ kb,
    float* __restrict__ avg) {
  __shared__ __attribute__((aligned(16))) unsigned short sQ[128 * 64];
  __shared__ __attribute__((aligned(16))) unsigned short sK[128 * 64];
  const int ss0 = blockIdx.x * 128, l0 = blockIdx.y * 128, b = blockIdx.z;
  const int tid = threadIdx.x, wave = tid >> 6, lane = tid & 63;
  const int quad = lane >> 4, l16 = lane & 15;
  const int wm = (wave & 1) * 64, wn = (wave >> 1) * 32;
  const int sr8 = lane >> 3, sc8 = lane & 7;

  f32x4 av[4][2];
  for (int mi = 0; mi < 4; ++mi)
    for (int ni = 0; ni < 2; ++ni) av[mi][ni] = (f32x4){0.f, 0.f, 0.f, 0.f};

  for (int h = 0; h < NHEAD; ++h) {
    const unsigned short* qg = qb + ((size_t)(b * NHEAD + h) * L_SEQ + l0) * HD;
    const unsigned short* kg = kb + ((size_t)(b * NHEAD + h) * L_SEQ + ss0) * HD;
    __syncthreads();
    for (int i = 0; i < 2; ++i) {
      const int p = wave * 2 + i;
      const int r = p * 8 + sr8;
      const int c = sc8 ^ (r & 7);
      gl_lds16(qg + (size_t)r * HD + c * 8, sQ + p * 512);
      gl_lds16(kg + (size_t)r * HD + c * 8, sK + p * 512);
    }
    __syncthreads();
    f32x4 scr[4][2];
    for (int mi = 0; mi < 4; ++mi)
      for (int ni = 0; ni < 2; ++ni) scr[mi][ni] = (f32x4){0.f, 0.f, 0.f, 0.f};
    for (int kk = 0; kk < HD; kk += 32) {
      bf16x8 a[4], bb[2];
      for (int mi = 0; mi < 4; ++mi) {
        const int r = wm + mi * 16 + l16;
        const int c = ((kk >> 3) + quad) ^ (r & 7);
        a[mi] = *(const bf16x8*)(sQ + r * 64 + c * 8);
      }
      for (int ni = 0; ni < 2; ++ni) {
        const int r = wn + ni * 16 + l16;
        const int c = ((kk >> 3) + quad) ^ (r & 7);
        bb[ni] = *(const bf16x8*)(sK + r * 64 + c * 8);
      }
      for (int mi = 0; mi < 4; ++mi)
        for (int ni = 0; ni < 2; ++ni)
          scr[mi][ni] = mfma16(a[mi], bb[ni], scr[mi][ni]);
    }
    for (int mi = 0; mi < 4; ++mi)
      for (int ni = 0; ni < 2; ++ni)
        for (int r = 0; r < 4; ++r)
          av[mi][ni][r] += fast_sigmoid(scr[mi][ni][r]);
  }

  for (int mi = 0; mi < 4; ++mi) {
    for (int r = 0; r < 4; ++r) {
      const int l = l0 + wm + mi * 16 + quad * 4 + r;
      float* dst = avg + ((size_t)b * L_SEQ + l) * L_SEQ + ss0 + wn;
      for (int ni = 0; ni < 2; ++ni)
        dst[ni * 16 + l16] = av[mi][ni][r] * 0.0625f;
    }
  }
}

// ---------------------------------------------------------------- K4: outproj
__global__ __launch_bounds__(256) void k_outproj(
    const unsigned short* __restrict__ OH, const unsigned short* __restrict__ Wob,
    const float* __restrict__ ob, float* __restrict__ out) {
  __shared__ __attribute__((aligned(16))) unsigned short sA[128 * 32];
  __shared__ __attribute__((aligned(16))) unsigned short sB[128 * 32];
  const int n0 = blockIdx.x * 128, m0 = blockIdx.y * 128;
  f32x4 acc[4][4];
  gemm_core(OH, Wob, m0, n0, sA, sB, acc);

  const int tid = threadIdx.x, wave = tid >> 6, lane = tid & 63;
  const int quad = lane >> 4, l16 = lane & 15;
  const int wm = (wave >> 1) * 64, wn = (wave & 1) * 64;
  for (int ni = 0; ni < 4; ++ni) {
    const int n = n0 + wn + ni * 16 + l16;
    const float bv = ob[n];
    for (int mi = 0; mi < 4; ++mi) {
      for (int r = 0; r < 4; ++r) {
        const int m = m0 + wm + mi * 16 + quad * 4 + r;
        const int b = m >> 11, l = m & (L_SEQ - 1);
        out[((size_t)l * NBATCH + b) * EMB + n] = acc[mi][ni][r] + bv;
      }
    }
  }
}

extern "C" void kernel_launch(void* const* d_in, const int* in_sizes, int n_in,
                              void* d_out, int out_size, void* d_ws, size_t ws_size,
                              hipStream_t stream) {
  (void)in_sizes; (void)n_in; (void)out_size;
  const float* qin = (const float*)d_in[0];
  const float* kin = (const float*)d_in[1];
  const float* vin = (const float*)d_in[2];
  const float* w   = (const float*)d_in[3];
  const float* bias = (const float*)d_in[4];
  const float* wo  = (const float*)d_in[5];
  const float* ob  = (const float*)d_in[6];
  float* out = (float*)d_out;

  unsigned short* Xq  = (unsigned short*)d_ws;
  unsigned short* Xk  = Xq + (size_t)MROWS * EMB;
  unsigned short* Xv  = Xk + (size_t)MROWS * EMB;
  unsigned short* Wb  = Xv + (size_t)MROWS * EMB;
  unsigned short* Wob = Wb + (size_t)3 * EMB * EMB;
  unsigned short* qbuf = Wob + (size_t)EMB * EMB;
  unsigned short* kbuf = qbuf + (size_t)MROWS * EMB;
  unsigned short* vbuf = kbuf + (size_t)MROWS * EMB;
  unsigned short* ohb  = vbuf + (size_t)MROWS * EMB;
  const size_t need = ((size_t)MROWS * EMB * 7 + (size_t)4 * EMB * EMB) * 2;
  if (ws_size < need) return;

  k_convert<<<16384, 256, 0, stream>>>(qin, kin, vin, w, wo, Xq, Xk, Xv, Wb, Wob);
  k_inproj<<<dim3(8, 32, 3), 256, 0, stream>>>(Xq, Xk, Xv, Wb, bias, qbuf, kbuf, vbuf);
  k_attn<<<dim3(32, 16), 512, 0, stream>>>(qbuf, kbuf, vbuf, ohb);
  k_avg<<<dim3(16, 16, 2), 512, 0, stream>>>(qbuf, kbuf, out + (size_t)MROWS * EMB);
  k_outproj<<<dim3(8, 32), 256, 0, stream>>>(ohb, Wob, ob, out);
}